// Round 13
// baseline (659.091 us; speedup 1.0000x reference)
//
#include <hip/hip_runtime.h>

// Problem constants (fixed by reference)
#define NE 8
#define TT 2048            // tokens per expert
#define KD 2048            // INPUT_SIZE  (K)
#define ND 8192            // OUTPUT_SIZE (N)
#define MT (NE * TT)       // 16384 total rows
#define NW ((size_t)NE * ND * KD)   // 134217728 weight elems
#define NX ((size_t)MT * KD)        // 33554432 input elems

typedef int   i32x4 __attribute__((ext_vector_type(4)));
typedef float f32x4 __attribute__((ext_vector_type(4)));

// ---------------- K1: partial abs-sum (f64, deterministic) ----------------
__global__ void k_abs_partial(const float* __restrict__ w, double* __restrict__ part) {
    __shared__ double sred[256];
    const size_t n4 = NW / 4;
    const size_t stride = (size_t)gridDim.x * blockDim.x;
    double acc = 0.0;
    for (size_t i = (size_t)blockIdx.x * blockDim.x + threadIdx.x; i < n4; i += stride) {
        float4 v = ((const float4*)w)[i];
        acc += (double)fabsf(v.x) + (double)fabsf(v.y) + (double)fabsf(v.z) + (double)fabsf(v.w);
    }
    sred[threadIdx.x] = acc;
    __syncthreads();
    for (int s = 128; s > 0; s >>= 1) {
        if ((int)threadIdx.x < s) sred[threadIdx.x] += sred[threadIdx.x + s];
        __syncthreads();
    }
    if (threadIdx.x == 0) part[blockIdx.x] = sred[0];
}

// ---------------- K2: finalize scale ----------------
__global__ void k_finalize(const double* __restrict__ part, double* __restrict__ sc) {
    __shared__ double sred[256];
    double a = 0.0;
    for (int i = threadIdx.x; i < 2048; i += 256) a += part[i];
    sred[threadIdx.x] = a;
    __syncthreads();
    for (int s = 128; s > 0; s >>= 1) {
        if ((int)threadIdx.x < s) sred[threadIdx.x] += sred[threadIdx.x + s];
        __syncthreads();
    }
    if (threadIdx.x == 0) {
        double mean = sred[0] / (double)NW;
        double denom = mean > 1e-5 ? mean : 1e-5;
        sc[0] = 1.0 / denom;   // scale
        sc[1] = denom;         // 1/scale (output multiplier)
    }
}

// ---------------- K3: quantize w -> ternary i8 ----------------
__global__ void k_quant(const float* __restrict__ w, const double* __restrict__ sc,
                        signed char* __restrict__ q) {
    const double scale = sc[0];
    const size_t n4 = NW / 4;
    const size_t stride = (size_t)gridDim.x * blockDim.x;
    for (size_t i = (size_t)blockIdx.x * blockDim.x + threadIdx.x; i < n4; i += stride) {
        float4 v = ((const float4*)w)[i];
        const int a = (int)fmin(fmax(rint((double)v.x * scale), -1.0), 1.0);
        const int b = (int)fmin(fmax(rint((double)v.y * scale), -1.0), 1.0);
        const int c = (int)fmin(fmax(rint((double)v.z * scale), -1.0), 1.0);
        const int d = (int)fmin(fmax(rint((double)v.w * scale), -1.0), 1.0);
        ((int*)q)[i] = (a & 0xff) | ((b & 0xff) << 8) | ((c & 0xff) << 16) | (d << 24);
    }
}

// ---------------- K4: x -> per-row i8 (scale = rowmax/127) ----------------
__global__ void k_xq(const float* __restrict__ x, signed char* __restrict__ xq,
                     float* __restrict__ rscale) {
    const int lane = (int)threadIdx.x & 63;
    const int w    = (int)threadIdx.x >> 6;
    const int row  = blockIdx.x * 4 + w;          // one wave per token row
    const float* xr = x + (size_t)row * KD;
    float4 v[8];
    float mx = 0.f;
#pragma unroll
    for (int j = 0; j < 8; ++j) {
        v[j] = ((const float4*)xr)[lane + 64 * j];
        mx = fmaxf(mx, fmaxf(fmaxf(fabsf(v[j].x), fabsf(v[j].y)),
                             fmaxf(fabsf(v[j].z), fabsf(v[j].w))));
    }
#pragma unroll
    for (int s = 32; s > 0; s >>= 1) mx = fmaxf(mx, __shfl_xor(mx, s));
    const float mxs = fmaxf(mx, 1e-20f);
    if (lane == 0) rscale[row] = mxs / 127.f;
    const float inv = 127.f / mxs;
    int* o = (int*)(xq + (size_t)row * KD);
#pragma unroll
    for (int j = 0; j < 8; ++j) {
        const int a = (int)rintf(v[j].x * inv);
        const int b = (int)rintf(v[j].y * inv);
        const int c = (int)rintf(v[j].z * inv);
        const int d = (int)rintf(v[j].w * inv);
        o[lane + 64 * j] = (a & 0xff) | ((b & 0xff) << 8) | ((c & 0xff) << 16) | (d << 24);
    }
}

// ---------------- K5: grouped GEMM, 256x256x64, i8 MFMA, 1 barrier/tile ----
// Round-12 verified data paths (swizzle pair, staging, C layout, numerics),
// but the tile is ONE phase: {RD12 (buf t) | STG4 (buf (t+2)%3) | lgkm0 |
// 32 MFMA | VM(4) | s_barrier}. Sync per tile: 1 barrier + 1 lgkm0 + 1 vmcnt
// (round 12 had 2 barriers-pairs + 2 lgkm0 -> ~740 cy/tile overhead measured).
// Race-freedom (ring-3): STG into buf[(t+2)%3] == buf[(t-1)%3] issues one
// barrier AFTER body t-1's lgkm0 retired all reads of that buffer.
// Counted VM(4) at tile end: 8 outstanding -> tile t+1's 4 landed, tile
// t+2's 4 stay in flight. Never drains same-body loads.
// gload imm stays 0 ALWAYS (nonzero shifts global AND LDS: round-4 NaN).

__device__ __forceinline__ void gload16(const void* g, void* l) {
    __builtin_amdgcn_global_load_lds(
        (const __attribute__((address_space(1))) unsigned int*)g,
        (__attribute__((address_space(3))) unsigned int*)l, 16, 0, 0);
}

#define BARR() asm volatile("s_barrier" ::: "memory")
#define SCHED0() __builtin_amdgcn_sched_barrier(0)
#define LGKM0() do { asm volatile("s_waitcnt lgkmcnt(0)" ::: "memory"); SCHED0(); } while (0)
#define VM(N) asm volatile("s_waitcnt vmcnt(" #N ")" ::: "memory")

// 12 fragment reads: 8 A + 4 B, base VGPR + compile-time imm (<= 7168)
#define RD12(AR, BR) do { \
  _Pragma("unroll") for (int m_ = 0; m_ < 8; ++m_) \
    af[m_] = *(const i32x4*)((AR) + m_ * 1024); \
  _Pragma("unroll") for (int n_ = 0; n_ < 4; ++n_) \
    bf[n_] = *(const i32x4*)((BR) + n_ * 1024); \
} while (0)

// stage one full tile (A 16K + B 16K) into buffer at byte SB: 4 gloads/wave
#define STG4(SB) do { \
    gload16(pA0, dstc + (SB)); \
    gload16(pA1, dstc + (SB) + 1024); \
    gload16(pB0, dstc + (SB) + 16384); \
    gload16(pB1, dstc + (SB) + 17408); \
    pA0 += 64; pA1 += 64; pB0 += 64; pB1 += 64; \
    asm volatile("" : "+v"(pA0), "+v"(pA1), "+v"(pB0), "+v"(pB1)); \
} while (0)

#define MM32() do { \
  __builtin_amdgcn_s_setprio(1); \
  _Pragma("unroll") for (int m_ = 0; m_ < 8; ++m_) \
    _Pragma("unroll") for (int n_ = 0; n_ < 4; ++n_) \
      acc[m_][n_] = __builtin_amdgcn_mfma_i32_16x16x64_i8( \
          af[m_], bf[n_], acc[m_][n_], 0, 0, 0); \
  __builtin_amdgcn_s_setprio(0); } while (0)

// one K-tile, single phase, single barrier
#define TILE_S(AR, BR, SB) do { \
    RD12(AR, BR); \
    STG4(SB); \
    LGKM0(); \
    MM32(); \
    VM(4); BARR(); \
} while (0)

__global__ __launch_bounds__(512, 2)
void k_gemm(const signed char* __restrict__ xq, const signed char* __restrict__ wq,
            const double* __restrict__ sc, const float* __restrict__ rscale,
            float* __restrict__ out) {
    __shared__ char lds[3 * 32768];   // ring-3, 96 KiB

    const int lane = (int)threadIdx.x & 63;
    const int wid  = (int)threadIdx.x >> 6;   // 0..7
    const int wr   = wid >> 2;                 // 0..1  (M strip of 128)
    const int wc   = wid & 3;                  // 0..3  (N strip of 64)
    const int li   = lane & 15;
    const int sl   = lane >> 4;                // k-slot 0..3 (16 B each)

    // XCD-aware swizzle + round-6 block mapping (FETCH ~compulsory proven)
    const int wg = ((int)blockIdx.x & 7) * 256 + ((int)blockIdx.x >> 3);
    const int e  = wg >> 8;
    const int u  = wg & 255;
    const int mt = (u >> 1) & 7;
    const int nt = (((u >> 4) << 1) | (u & 1));

    const signed char* Ab = xq + ((size_t)e * TT + (size_t)mt * 256) * KD;
    const signed char* Bb = wq + ((size_t)e * ND + (size_t)nt * 256) * KD;
    float*             Cb = out + ((size_t)e * TT + (size_t)mt * 256) * ND + (size_t)nt * 256;

    const float sfac = (float)sc[1];
    const float* rsc = rscale + (size_t)e * TT + (size_t)mt * 256 + wr * 128;
    asm volatile("s_waitcnt vmcnt(0)" ::: "memory");

    // read bases (verified swizzle: phys slot = sl ^ (li&3) ^ ((li>>2)&3))
    const int pA = (sl ^ (lane & 3) ^ ((lane >> 2) & 3)) & 3;
    const char* aR0 = (const char*)lds + ((wr * 128 + li) << 6) + (pA << 4);
    const char* bR0 = (const char*)lds + 16384 + ((wc * 64 + li) << 6) + (pA << 4);
    const char* aR1 = aR0 + 32768;
    const char* bR1 = bR0 + 32768;
    const char* aR2 = aR0 + 65536;
    const char* bR2 = bR0 + 65536;

    // staging (verified inverse-swizzle source): chunk = 16 rows x 64 B
    const int lslot = (lane & 3) ^ ((lane >> 2) & 3) ^ ((lane >> 4) & 3);
    char* dstc = (char*)lds + wid * 2048;
    const int srow0 = (wid * 2 + 0) * 16 + (lane >> 2);   // 0..255
    const int srow1 = (wid * 2 + 1) * 16 + (lane >> 2);
    const char* pA0 = (const char*)(Ab + (size_t)srow0 * KD + lslot * 16);
    const char* pA1 = (const char*)(Ab + (size_t)srow1 * KD + lslot * 16);
    const char* pB0 = (const char*)(Bb + (size_t)srow0 * KD + lslot * 16);
    const char* pB1 = (const char*)(Bb + (size_t)srow1 * KD + lslot * 16);

    i32x4 acc[8][4];
#pragma unroll
    for (int m = 0; m < 8; ++m)
#pragma unroll
        for (int n = 0; n < 4; ++n) acc[m][n] = (i32x4){0, 0, 0, 0};

    i32x4 af[8], bf[4];

    // prologue: stage tiles 0,1 -> buf0,buf1; wait tile 0
    STG4(0);
    STG4(32768);
    VM(4);
    BARR();

    // tiles 0..29 (3 per iteration; stages tiles 2..31)
#pragma unroll 1
    for (int j = 0; j < 10; ++j) {
        TILE_S(aR0, bR0, 65536);   // t%3==0: read buf0, stage buf2
        TILE_S(aR1, bR1, 0);       // t%3==1: read buf1, stage buf0
        TILE_S(aR2, bR2, 32768);   // t%3==2: read buf2, stage buf1
    }
    // tile 30: read buf0, no stage; ensure tile 31 landed
    RD12(aR0, bR0);
    LGKM0();
    MM32();
    VM(0); BARR();
    // tile 31: read buf1
    RD12(aR1, bR1);
    LGKM0();
    MM32();

    // ---- epilogue: out = acc_i32 * s * rowscale, f32 store ----
#pragma unroll
    for (int m = 0; m < 8; ++m) {
        float fac[4];
#pragma unroll
        for (int r4 = 0; r4 < 4; ++r4)
            fac[r4] = sfac * rsc[m * 16 + sl * 4 + r4];
#pragma unroll
        for (int n = 0; n < 4; ++n)
#pragma unroll
            for (int r4 = 0; r4 < 4; ++r4) {
                const int row = wr * 128 + m * 16 + sl * 4 + r4;
                const int col = wc * 64 + n * 16 + li;
                Cb[(size_t)row * ND + col] = (float)acc[m][n][r4] * fac[r4];
            }
    }
}

// ---------------- fallback (only if ws too small): f32 tiled, on-the-fly quant ----------------
__global__ void k_fallback(const float* __restrict__ x, const float* __restrict__ w,
                           const double* __restrict__ sc, float* __restrict__ out) {
    const int row0 = blockIdx.x * 16;
    const int col0 = blockIdx.y * 16;
    const int e = row0 / TT;
    __shared__ float xs[16][17];
    __shared__ float wq[16][17];
    const double scale = sc[0];
    const float s = (float)sc[1];
    const int tx = threadIdx.x, ty = threadIdx.y;
    const float* wbase = w + ((size_t)e * ND + col0) * KD;
    float acc = 0.f;
    for (int k0 = 0; k0 < KD; k0 += 16) {
        xs[ty][tx] = x[(size_t)(row0 + ty) * KD + k0 + tx];
        const float wv = wbase[(size_t)ty * KD + k0 + tx];
        wq[ty][tx] = (float)fmin(fmax(rint((double)wv * scale), -1.0), 1.0);
        __syncthreads();
#pragma unroll
        for (int kk = 0; kk < 16; ++kk) acc += xs[ty][kk] * wq[tx][kk];
        __syncthreads();
    }
    out[(size_t)(row0 + ty) * ND + col0 + tx] = acc * s;
}

// ---------------- launch ----------------
extern "C" void kernel_launch(void* const* d_in, const int* in_sizes, int n_in,
                              void* d_out, int out_size, void* d_ws, size_t ws_size,
                              hipStream_t stream) {
    const float* x = (const float*)d_in[0];
    const float* w = (const float*)d_in[1];
    float* out = (float*)d_out;

    double* part   = (double*)d_ws;                        // 16 KiB
    double* sc     = (double*)((char*)d_ws + 16384);       // scale, 1/scale
    float*  rscale = (float*)((char*)d_ws + 32768);        // 64 KiB (16384 rows)
    signed char* xq = (signed char*)((char*)d_ws + 98304); // NX bytes
    signed char* wq = xq + NX;                             // NW bytes

    const size_t need = 98304 + NX + NW;                   // ~160 MiB

    hipLaunchKernelGGL(k_abs_partial, dim3(2048), dim3(256), 0, stream, w, part);
    hipLaunchKernelGGL(k_finalize,   dim3(1),    dim3(256), 0, stream, part, sc);

    if (ws_size >= need) {
        hipLaunchKernelGGL(k_quant, dim3(2048), dim3(256), 0, stream, w, sc, wq);
        hipLaunchKernelGGL(k_xq,    dim3(MT / 4), dim3(256), 0, stream, x, xq, rscale);
        hipLaunchKernelGGL(k_gemm,  dim3(NE * (TT / 256) * (ND / 256)), dim3(512), 0, stream,
                           xq, wq, sc, rscale, out);
    } else {
        dim3 grid(MT / 16, ND / 16);
        hipLaunchKernelGGL(k_fallback, grid, dim3(16, 16), 0, stream, x, w, sc, out);
    }
}